// Round 4
// baseline (107.052 us; speedup 1.0000x reference)
//
#include <hip/hip_runtime.h>

// Problem constants
#define HWp    1024          // patches per image (32*32)
#define NPATCH 4096          // B * HWp
#define WSTR   68            // padded stride: 64 conv ch + 1 temp ch + 3 pad
#define KDIM   4096          // 64 ci * 8 * 8
#define KB     32            // K-split chunks (compile-time)
#define NCI    2             // input channels per chunk = 64/KB

// Workspace layout (float offsets)
#define WT_OFF    0u         // [4096][68] folded transposed weights
#define BIASP_OFF 278528u    // [64] folded conv biases
#define WSUM_OFF  278592u    // [64] channel-sum of conv2_w
#define MISC_OFF  278656u    // [0]=bias_t
#define PS_OFF    278672u    // [4][4096] partial s (per channel-quarter)
#define TPART_OFF 295056u    // [4096] temp-channel conv sum (pre-bias)
#define PART_OFF  299152u    // [KB][65][4096] channel-major conv partials

typedef __attribute__((address_space(1))) const void GVOID;
typedef __attribute__((address_space(3))) void LVOID;

// ---------------------------------------------------------------------------
// Prep: fold BN into conv weights/biases, transpose weights to [k][ch].
// ---------------------------------------------------------------------------
__global__ void prep_kernel(
    const float* __restrict__ conv1_w, const float* __restrict__ conv1_b,
    const float* __restrict__ g,  const float* __restrict__ bb,
    const float* __restrict__ m,  const float* __restrict__ v,
    const float* __restrict__ conv2_w, const float* __restrict__ conv2_b,
    const float* __restrict__ tconv_w, const float* __restrict__ tconv_b,
    const float* __restrict__ tg, const float* __restrict__ tb,
    const float* __restrict__ tm, const float* __restrict__ tv,
    float* __restrict__ ws)
{
    float* Wt = ws + WT_OFF;
    if (blockIdx.x < 16) {
        int k = blockIdx.x * 256 + threadIdx.x;   // 0..4095
        float At = tg[0] / sqrtf(tv[0] + 1e-5f);
        #pragma unroll 8
        for (int c = 0; c < 64; ++c) {
            float A = g[c] / sqrtf(v[c] + 1e-5f);
            Wt[(size_t)k * WSTR + c] = A * conv1_w[(size_t)c * KDIM + k];
        }
        Wt[(size_t)k * WSTR + 64] = At * tconv_w[k];
        Wt[(size_t)k * WSTR + 65] = 0.0f;
        Wt[(size_t)k * WSTR + 66] = 0.0f;
        Wt[(size_t)k * WSTR + 67] = 0.0f;
    } else {
        int t = threadIdx.x;
        if (t < 64) {
            float A = g[t] / sqrtf(v[t] + 1e-5f);
            ws[BIASP_OFF + t] = A * (conv1_b[t] - m[t]) + bb[t];
            float s = 0.f;
            for (int co = 0; co < 64; ++co) s += conv2_w[co * 64 + t];
            ws[WSUM_OFF + t] = s;
        } else if (t == 64) {
            float At = tg[0] / sqrtf(tv[0] + 1e-5f);
            ws[MISC_OFF + 0] = At * (tconv_b[0] - tm[0]) + tb[0];
        }
    }
}

// ---------------------------------------------------------------------------
// Patch conv, fp32. Block = 256 threads = 4 waves, 128 patches per block
// (2 per lane). Wave w computes channels [16w,16w+16); wave 0 also does the
// temperature channel. Weights staged in half-ci chunks (32 k-rows = 8.7KB),
// double-buffered via global_load_lds. LDS total 17.4KB -> more blocks/CU.
// All accumulators are NAMED SCALARS.
// ---------------------------------------------------------------------------
// stage one half-chunk (2176 floats = 544 x 16B) into LDS at float off DSTF
#define STAGE(DSTF, SRCP)                                                     \
    do {                                                                      \
        const float* _s = (SRCP);                                             \
        __builtin_amdgcn_global_load_lds((GVOID*)(_s + (size_t)t * 4),        \
            (LVOID*)&lds[(DSTF) + t * 4], 16, 0, 0);                          \
        __builtin_amdgcn_global_load_lds((GVOID*)(_s + (size_t)(256 + t) * 4),\
            (LVOID*)&lds[(DSTF) + (256 + t) * 4], 16, 0, 0);                  \
        if (t < 32)                                                           \
            __builtin_amdgcn_global_load_lds(                                 \
                (GVOID*)(_s + (size_t)(512 + t) * 4),                         \
                (LVOID*)&lds[(DSTF) + (512 + t) * 4], 16, 0, 0);              \
    } while (0)

#define FMAB(XK0, XK1, WROW, TEMP)                                            \
    do {                                                                      \
        const float* _w = (WROW);                                             \
        float4 _w0 = *(const float4*)(_w + cbase);                            \
        float4 _w1 = *(const float4*)(_w + cbase + 4);                        \
        float4 _w2 = *(const float4*)(_w + cbase + 8);                        \
        float4 _w3 = *(const float4*)(_w + cbase + 12);                       \
        float _x0 = (XK0), _x1 = (XK1);                                       \
        a0  = fmaf(_w0.x, _x0, a0);   b0  = fmaf(_w0.x, _x1, b0);             \
        a1  = fmaf(_w0.y, _x0, a1);   b1  = fmaf(_w0.y, _x1, b1);             \
        a2  = fmaf(_w0.z, _x0, a2);   b2  = fmaf(_w0.z, _x1, b2);             \
        a3  = fmaf(_w0.w, _x0, a3);   b3  = fmaf(_w0.w, _x1, b3);             \
        a4  = fmaf(_w1.x, _x0, a4);   b4  = fmaf(_w1.x, _x1, b4);             \
        a5  = fmaf(_w1.y, _x0, a5);   b5  = fmaf(_w1.y, _x1, b5);             \
        a6  = fmaf(_w1.z, _x0, a6);   b6  = fmaf(_w1.z, _x1, b6);             \
        a7  = fmaf(_w1.w, _x0, a7);   b7  = fmaf(_w1.w, _x1, b7);             \
        a8  = fmaf(_w2.x, _x0, a8);   b8  = fmaf(_w2.x, _x1, b8);             \
        a9  = fmaf(_w2.y, _x0, a9);   b9  = fmaf(_w2.y, _x1, b9);             \
        a10 = fmaf(_w2.z, _x0, a10);  b10 = fmaf(_w2.z, _x1, b10);            \
        a11 = fmaf(_w2.w, _x0, a11);  b11 = fmaf(_w2.w, _x1, b11);            \
        a12 = fmaf(_w3.x, _x0, a12);  b12 = fmaf(_w3.x, _x1, b12);            \
        a13 = fmaf(_w3.y, _x0, a13);  b13 = fmaf(_w3.y, _x1, b13);            \
        a14 = fmaf(_w3.z, _x0, a14);  b14 = fmaf(_w3.z, _x1, b14);            \
        a15 = fmaf(_w3.w, _x0, a15);  b15 = fmaf(_w3.w, _x1, b15);            \
        if (TEMP) {                                                           \
            float _wt = _w[64];                                               \
            at = fmaf(_wt, _x0, at);  bt = fmaf(_wt, _x1, bt);                \
        }                                                                     \
    } while (0)

#define HALF_COMPUTE(TEMP)                                                    \
    _Pragma("unroll")                                                         \
    for (int j = 0; j < 4; ++j) {                                             \
        const float* _xr = xh + j * 256;                                      \
        float4 p00 = *(const float4*)(_xr);                                   \
        float4 p01 = *(const float4*)(_xr + 4);                               \
        float4 p10 = *(const float4*)(_xr + 4096);                            \
        float4 p11 = *(const float4*)(_xr + 4096 + 4);                        \
        const float* wrow = &lds[bufF + j * 8 * WSTR];                        \
        FMAB(p00.x, p10.x, wrow,            TEMP);                            \
        FMAB(p00.y, p10.y, wrow + WSTR,     TEMP);                            \
        FMAB(p00.z, p10.z, wrow + 2 * WSTR, TEMP);                            \
        FMAB(p00.w, p10.w, wrow + 3 * WSTR, TEMP);                            \
        FMAB(p01.x, p11.x, wrow + 4 * WSTR, TEMP);                            \
        FMAB(p01.y, p11.y, wrow + 5 * WSTR, TEMP);                            \
        FMAB(p01.z, p11.z, wrow + 6 * WSTR, TEMP);                            \
        FMAB(p01.w, p11.w, wrow + 7 * WSTR, TEMP);                            \
    }

__global__ __launch_bounds__(256, 4) void conv_kernel(
    const float* __restrict__ x, const float* __restrict__ ws_ro,
    float* __restrict__ part)
{
    __shared__ __align__(16) float lds[4352];  // 2 x 2176 stage / 4 x 1056 trans
    int t    = threadIdx.x;
    int wv   = __builtin_amdgcn_readfirstlane(t >> 6);
    int lane = t & 63;
    int mb   = blockIdx.x;        // 32 patch-blocks of 128
    int kb   = blockIdx.y;        // KB K-chunks
    int b    = mb >> 3;           // 8 blocks per image
    int gp0  = mb * 128 + lane;   // lane's first patch (second = +64)
    int py0  = (gp0 >> 5) & 31;
    int px0  = gp0 & 31;
    int cbase = wv * 16;

    const float* wchunk = ws_ro + WT_OFF + (size_t)(kb * NCI) * 64 * WSTR;
    const float* xpat   = x + ((size_t)(b * 64 + kb * NCI) << 16)
                            + py0 * 2048 + px0 * 8;

    float a0=0,a1=0,a2=0,a3=0,a4=0,a5=0,a6=0,a7=0;
    float a8=0,a9=0,a10=0,a11=0,a12=0,a13=0,a14=0,a15=0;
    float b0=0,b1=0,b2=0,b3=0,b4=0,b5=0,b6=0,b7=0;
    float b8=0,b9=0,b10=0,b11=0,b12=0,b13=0,b14=0,b15=0;
    float at=0, bt=0;

    STAGE(0, wchunk);
    __syncthreads();

    const int halves = 2 * NCI;
    for (int h = 0; h < halves; ++h) {
        int bufF = (h & 1) * 2176;
        if (h + 1 < halves)
            STAGE(bufF ^ 2176, wchunk + (size_t)(h + 1) * 2176);
        const float* xh = xpat + ((size_t)(h >> 1) << 16) + (h & 1) * 1024;
        if (wv == 0) { HALF_COMPUTE(1) } else { HALF_COMPUTE(0) }
        __syncthreads();
    }

    // Per-wave transpose (8 rows at a time) into own LDS region, then
    // coalesced float2 stores to channel-major partials [kb][65][4096].
    int base = wv * 1056;
    float* prow0 = part + (size_t)kb * 65 * NPATCH + (size_t)mb * 128 + 2 * lane;

    #define TROW(R, VA, VB)                                 \
        lds[base + (R) * 132 + lane] = VA;                  \
        lds[base + (R) * 132 + 64 + lane] = VB;
    TROW(0,a0,b0) TROW(1,a1,b1) TROW(2,a2,b2) TROW(3,a3,b3)
    TROW(4,a4,b4) TROW(5,a5,b5) TROW(6,a6,b6) TROW(7,a7,b7)
    #pragma unroll
    for (int r = 0; r < 8; ++r) {
        float2 vv = *(float2*)&lds[base + r * 132 + 2 * lane];
        *(float2*)(prow0 + (size_t)(cbase + r) * NPATCH) = vv;
    }
    TROW(0,a8,b8)   TROW(1,a9,b9)   TROW(2,a10,b10) TROW(3,a11,b11)
    TROW(4,a12,b12) TROW(5,a13,b13) TROW(6,a14,b14) TROW(7,a15,b15)
    #pragma unroll
    for (int r = 0; r < 8; ++r) {
        float2 vv = *(float2*)&lds[base + r * 132 + 2 * lane];
        *(float2*)(prow0 + (size_t)(cbase + 8 + r) * NPATCH) = vv;
    }
    if (wv == 0) {
        TROW(0, at, bt)
        float2 vv = *(float2*)&lds[base + 2 * lane];
        *(float2*)(prow0 + (size_t)64 * NPATCH) = vv;
    }
    #undef TROW
}

// ---------------------------------------------------------------------------
// Finalize: grid (64 patch-blocks x 4 channel-quarters). Lane = patch,
// wave = 4-channel group; KB-loop fully unrolled -> 32 coalesced independent
// loads in flight per channel. Emits per-quarter partial s (ReLU per channel
// commutes with the quarter split) and the raw temp-channel sum.
// ---------------------------------------------------------------------------
__global__ __launch_bounds__(256) void finalize_kernel(
    float* ws, const float* __restrict__ part)
{
    __shared__ float red[4][64];
    int t    = threadIdx.x;
    int wv   = t >> 6;
    int lane = t & 63;
    int m    = blockIdx.x;        // 64
    int cq   = blockIdx.y;        // 4
    int gp   = m * 64 + lane;
    int c0   = cq * 16 + wv * 4;

    float s = 0.f;
    #pragma unroll 2
    for (int cc = 0; cc < 4; ++cc) {
        int c = c0 + cc;
        const float* pc = part + (size_t)c * NPATCH + gp;
        float v = 0.f;
        #pragma unroll
        for (int kb = 0; kb < KB; ++kb)
            v += pc[(size_t)kb * 65 * NPATCH];
        s += ws[WSUM_OFF + c] * fmaxf(v + ws[BIASP_OFF + c], 0.f);
    }
    red[wv][lane] = s;
    __syncthreads();
    if (wv == 0)
        ws[PS_OFF + (size_t)cq * NPATCH + gp] =
            red[0][lane] + red[1][lane] + red[2][lane] + red[3][lane];
    if (cq == 0 && wv == 1) {
        const float* pt = part + (size_t)64 * NPATCH + gp;
        float v = 0.f;
        #pragma unroll
        for (int kb = 0; kb < KB; ++kb)
            v += pt[(size_t)kb * 65 * NPATCH];
        ws[TPART_OFF + gp] = v;
    }
}

// ---------------------------------------------------------------------------
// Fused 4-iteration softmax. One WAVE per query patch row; 1024 logits in
// 16 registers/lane; wave-shuffle reductions only. s is assembled from the
// 4 per-quarter partials (the dropped sum(conv2_b) constant cancels in
// s_p - s_q).
// ---------------------------------------------------------------------------
__global__ __launch_bounds__(256) void softmax_kernel(
    const float* __restrict__ ws_ro, float* __restrict__ out)
{
    const float* ps0 = ws_ro + PS_OFF;
    const float* ps1 = ps0 + NPATCH;
    const float* ps2 = ps0 + 2 * NPATCH;
    const float* ps3 = ps0 + 3 * NPATCH;
    int t    = threadIdx.x;
    int wv   = t >> 6;
    int lane = t & 63;
    int gp   = blockIdx.x * 4 + wv;   // 0..4095
    int b    = gp >> 10;
    int p    = gp & 1023;
    float bt = ws_ro[MISC_OFF];
    float sq = ps0[gp] + ps1[gp] + ps2[gp] + ps3[gp];
    float tv = fmaxf(ws_ro[TPART_OFF + gp] + bt, 0.f);
    float iT = 1.0f / (0.025f + tv);
    const float4* s0 = (const float4*)(ps0 + (size_t)b * HWp);
    const float4* s1 = (const float4*)(ps1 + (size_t)b * HWp);
    const float4* s2 = (const float4*)(ps2 + (size_t)b * HWp);
    const float4* s3 = (const float4*)(ps3 + (size_t)b * HWp);

    float L[16];
    #pragma unroll
    for (int c4 = 0; c4 < 4; ++c4) {
        int idx = c4 * 64 + lane;
        float4 v0 = s0[idx], v1 = s1[idx], v2 = s2[idx], v3 = s3[idx];
        float svx = v0.x + v1.x + v2.x + v3.x;
        float svy = v0.y + v1.y + v2.y + v3.y;
        float svz = v0.z + v1.z + v2.z + v3.z;
        float svw = v0.w + v1.w + v2.w + v3.w;
        int q0 = c4 * 256 + lane * 4;
        float d0 = sq - svx, d1 = sq - svy, d2 = sq - svz, d3 = sq - svw;
        L[c4*4+0] = -d0 * d0 * iT;
        L[c4*4+1] = -d1 * d1 * iT;
        L[c4*4+2] = -d2 * d2 * iT;
        L[c4*4+3] = -d3 * d3 * iT;
        if (q0 + 0 == p) L[c4*4+0] -= 1000.f * iT;
        if (q0 + 1 == p) L[c4*4+1] -= 1000.f * iT;
        if (q0 + 2 == p) L[c4*4+2] -= 1000.f * iT;
        if (q0 + 3 == p) L[c4*4+3] -= 1000.f * iT;
    }

    size_t rowOff = (size_t)gp * HWp;
    #pragma unroll 1
    for (int it = 0; it < 4; ++it) {
        float mx = L[0];
        #pragma unroll
        for (int j = 1; j < 16; ++j) mx = fmaxf(mx, L[j]);
        #pragma unroll
        for (int off = 32; off; off >>= 1)
            mx = fmaxf(mx, __shfl_xor(mx, off, 64));
        float e[16];
        float sum = 0.f;
        #pragma unroll
        for (int j = 0; j < 16; ++j) { e[j] = __expf(L[j] - mx); sum += e[j]; }
        #pragma unroll
        for (int off = 32; off; off >>= 1)
            sum += __shfl_xor(sum, off, 64);
        float r = 1.0f / sum;
        #pragma unroll
        for (int j = 0; j < 16; ++j) e[j] *= r;
        float4* orow = (float4*)(out + (size_t)it * NPATCH * HWp + rowOff);
        #pragma unroll
        for (int c4 = 0; c4 < 4; ++c4) {
            float4 o;
            o.x = e[c4*4+0]; o.y = e[c4*4+1]; o.z = e[c4*4+2]; o.w = e[c4*4+3];
            orow[c4 * 64 + lane] = o;
        }
        if (it < 3) {
            #pragma unroll
            for (int j = 0; j < 16; ++j)
                L[j] += iT * __logf(1.0f - e[j] + 1e-45f);
        }
    }
}

// ---------------------------------------------------------------------------
extern "C" void kernel_launch(void* const* d_in, const int* in_sizes, int n_in,
                              void* d_out, int out_size, void* d_ws, size_t ws_size,
                              hipStream_t stream)
{
    (void)in_sizes; (void)n_in; (void)out_size; (void)ws_size;
    const float* x       = (const float*)d_in[0];
    const float* conv1_w = (const float*)d_in[1];
    const float* conv1_b = (const float*)d_in[2];
    const float* bn1_g   = (const float*)d_in[3];
    const float* bn1_b   = (const float*)d_in[4];
    const float* bn1_m   = (const float*)d_in[5];
    const float* bn1_v   = (const float*)d_in[6];
    const float* conv2_w = (const float*)d_in[7];
    const float* conv2_b = (const float*)d_in[8];
    const float* tconv_w = (const float*)d_in[9];
    const float* tconv_b = (const float*)d_in[10];
    const float* bnt_g   = (const float*)d_in[11];
    const float* bnt_b   = (const float*)d_in[12];
    const float* bnt_m   = (const float*)d_in[13];
    const float* bnt_v   = (const float*)d_in[14];

    float* ws  = (float*)d_ws;
    float* out = (float*)d_out;

    prep_kernel<<<dim3(17), dim3(256), 0, stream>>>(
        conv1_w, conv1_b, bn1_g, bn1_b, bn1_m, bn1_v,
        conv2_w, conv2_b, tconv_w, tconv_b, bnt_g, bnt_b, bnt_m, bnt_v, ws);

    conv_kernel<<<dim3(32, KB), dim3(256), 0, stream>>>(x, ws, ws + PART_OFF);

    finalize_kernel<<<dim3(64, 4), dim3(256), 0, stream>>>(ws, ws + PART_OFF);

    softmax_kernel<<<dim3(1024), dim3(256), 0, stream>>>(ws, out);
}

// Round 5
// 85.622 us; speedup vs baseline: 1.2503x; 1.2503x over previous
//
#include <hip/hip_runtime.h>

// Problem constants
#define HWp    1024          // patches per image (32*32)
#define NPATCH 4096          // B * HWp
#define KS     8             // K-split chunks
#define CIPC   8             // input channels per chunk (64/KS)

// Workspace layout (float offsets)
#define WQ_OFF    0u         // [64ci][16k4][64ch][4j] folded conv weights
#define WTT_OFF   262144u    // [4096] folded temp weights
#define BIASP_OFF 266240u    // [64] folded conv biases
#define WSUM_OFF  266304u    // [64] channel-sum of conv2_w
#define MISC_OFF  266368u    // [0]=bias_t
#define S_OFF     266384u    // [4096] channel-sum s
#define INVT_OFF  270480u    // [4096] 1/(0.025+t)
#define PART_OFF  274576u    // [KS][4096][64] conv partials
#define TPART_OFF 2371728u   // [KS][4096] temp partials

typedef __attribute__((address_space(1))) const void GVOID;
typedef __attribute__((address_space(3))) void LVOID;

// ---------------------------------------------------------------------------
// Prep: fold BN; weights to [ci][k4][ch][4] (k within ci = k4*4+j); temp
// weights to Wtt[k]; biases / wsum.
// ---------------------------------------------------------------------------
__global__ void prep_kernel(
    const float* __restrict__ conv1_w, const float* __restrict__ conv1_b,
    const float* __restrict__ g,  const float* __restrict__ bb,
    const float* __restrict__ m,  const float* __restrict__ v,
    const float* __restrict__ conv2_w, const float* __restrict__ conv2_b,
    const float* __restrict__ tconv_w, const float* __restrict__ tconv_b,
    const float* __restrict__ tg, const float* __restrict__ tb,
    const float* __restrict__ tm, const float* __restrict__ tv,
    float* __restrict__ ws)
{
    if (blockIdx.x < 16) {
        int k  = blockIdx.x * 256 + threadIdx.x;   // 0..4095
        int ci = k >> 6, kl = k & 63;
        int k4 = kl >> 2, j = kl & 3;
        float* wq = ws + WQ_OFF + (((size_t)ci * 16 + k4) * 64) * 4 + j;
        #pragma unroll 8
        for (int c = 0; c < 64; ++c) {
            float A = g[c] / sqrtf(v[c] + 1e-5f);
            wq[c * 4] = A * conv1_w[(size_t)c * 4096 + k];
        }
        float At = tg[0] / sqrtf(tv[0] + 1e-5f);
        ws[WTT_OFF + k] = At * tconv_w[k];
    } else {
        int t = threadIdx.x;
        if (t < 64) {
            float A = g[t] / sqrtf(v[t] + 1e-5f);
            ws[BIASP_OFF + t] = A * (conv1_b[t] - m[t]) + bb[t];
            float s = 0.f;
            for (int co = 0; co < 64; ++co) s += conv2_w[co * 64 + t];
            ws[WSUM_OFF + t] = s;
        } else if (t == 64) {
            float At = tg[0] / sqrtf(tv[0] + 1e-5f);
            ws[MISC_OFF + 0] = At * (tconv_b[0] - tm[0]) + tb[0];
        }
    }
}

// ---------------------------------------------------------------------------
// Patch conv. Lane = output channel, wave = 8 consecutive patches (one px
// row segment), block = 4 waves = 32 patches, blockIdx=(pgb 0..127, ks 0..7).
// Weights staged per-ci (16KB, double-buffered) via global_load_lds; read as
// 2 ds_read_b128 per (ci,ky) feeding 64 FMAs whose x operands are
// WAVE-UNIFORM scalar loads (SGPR operand of v_fmac). Accumulators: 8 named
// scalars. Temp channel: per-lane (patch,ky) slice, shuffle-reduced.
// ---------------------------------------------------------------------------
#define STAGE(DSTF, SRCP)                                                     \
    do {                                                                      \
        const float* _s = (SRCP);                                             \
        _Pragma("unroll")                                                     \
        for (int _c = 0; _c < 4; ++_c)                                        \
            __builtin_amdgcn_global_load_lds(                                 \
                (GVOID*)(_s + _c * 1024 + t * 4),                             \
                (LVOID*)&lds[(DSTF) + _c * 1024 + t * 4], 16, 0, 0);          \
    } while (0)

#define ACC8(W, KX)                                                           \
    do {                                                                      \
        float _w = (W);                                                       \
        a0 = fmaf(_w, xr[0 * 8 + (KX)], a0);                                  \
        a1 = fmaf(_w, xr[1 * 8 + (KX)], a1);                                  \
        a2 = fmaf(_w, xr[2 * 8 + (KX)], a2);                                  \
        a3 = fmaf(_w, xr[3 * 8 + (KX)], a3);                                  \
        a4 = fmaf(_w, xr[4 * 8 + (KX)], a4);                                  \
        a5 = fmaf(_w, xr[5 * 8 + (KX)], a5);                                  \
        a6 = fmaf(_w, xr[6 * 8 + (KX)], a6);                                  \
        a7 = fmaf(_w, xr[7 * 8 + (KX)], a7);                                  \
    } while (0)

__global__ __launch_bounds__(256, 4) void conv_kernel(
    const float* __restrict__ x, const float* __restrict__ ws_ro,
    float* __restrict__ part, float* __restrict__ tpart)
{
    __shared__ __align__(16) float lds[8192];   // 2 x 16KB weight buffers
    int t     = threadIdx.x;
    int wv    = __builtin_amdgcn_readfirstlane(t >> 6);
    int lane  = t & 63;
    int lane4 = lane * 4;
    int pgb   = blockIdx.x;       // 128: patch-row segments of 32
    int ks    = blockIdx.y;       // 8: K chunks
    int b     = pgb >> 5;         // image
    int py    = pgb & 31;
    int px0   = wv * 8;
    int gp0   = pgb * 32 + wv * 8;  // wave's first patch
    int ci0   = ks * CIPC;

    const float* wq = ws_ro + WQ_OFF + (size_t)ci0 * 4096;
    const float* xw = x + (((size_t)(b * 64 + ci0)) << 16) + py * 2048 + px0 * 8;

    // temp-channel mapping: lane -> (patch pt, row kyt)
    int pt  = lane >> 3;
    int kyt = lane & 7;
    const float* xt  = x + (((size_t)(b * 64 + ci0)) << 16) + py * 2048
                         + (px0 + pt) * 8 + kyt * 256;
    const float* wtt = ws_ro + WTT_OFF + ci0 * 64 + kyt * 8;

    float a0=0,a1=0,a2=0,a3=0,a4=0,a5=0,a6=0,a7=0;
    float tacc = 0.f;

    STAGE(0, wq);
    __syncthreads();

    for (int ci = 0; ci < CIPC; ++ci) {
        int bufF = (ci & 1) * 4096;
        if (ci + 1 < CIPC)
            STAGE(bufF ^ 4096, wq + (size_t)(ci + 1) * 4096);
        const float* wb = &lds[bufF];
        const float* xc = xw + ((size_t)ci << 16);   // wave-uniform
        #pragma unroll
        for (int ky = 0; ky < 8; ++ky) {
            float4 wA = *(const float4*)(wb + ky * 512 + lane4);        // kx 0..3
            float4 wB = *(const float4*)(wb + ky * 512 + 256 + lane4);  // kx 4..7
            const float* xr = xc + ky * 256;                            // uniform
            ACC8(wA.x, 0); ACC8(wA.y, 1); ACC8(wA.z, 2); ACC8(wA.w, 3);
            ACC8(wB.x, 4); ACC8(wB.y, 5); ACC8(wB.z, 6); ACC8(wB.w, 7);
        }
        // temp channel: per-lane 8 elements of (pt, kyt) row
        {
            const float* xtp = xt + ((size_t)ci << 16);
            float4 x0 = *(const float4*)(xtp);
            float4 x1 = *(const float4*)(xtp + 4);
            const float* wt = wtt + ci * 64;
            float4 w0 = *(const float4*)(wt);
            float4 w1 = *(const float4*)(wt + 4);
            tacc = fmaf(w0.x, x0.x, tacc); tacc = fmaf(w0.y, x0.y, tacc);
            tacc = fmaf(w0.z, x0.z, tacc); tacc = fmaf(w0.w, x0.w, tacc);
            tacc = fmaf(w1.x, x1.x, tacc); tacc = fmaf(w1.y, x1.y, tacc);
            tacc = fmaf(w1.z, x1.z, tacc); tacc = fmaf(w1.w, x1.w, tacc);
        }
        __syncthreads();
    }

    // epilogue: coalesced 256B rows per patch
    float* prow = part + ((size_t)ks * NPATCH + gp0) * 64 + lane;
    prow[0 * 64] = a0; prow[1 * 64] = a1; prow[2 * 64] = a2; prow[3 * 64] = a3;
    prow[4 * 64] = a4; prow[5 * 64] = a5; prow[6 * 64] = a6; prow[7 * 64] = a7;

    tacc += __shfl_xor(tacc, 1, 64);
    tacc += __shfl_xor(tacc, 2, 64);
    tacc += __shfl_xor(tacc, 4, 64);
    if (kyt == 0)
        tpart[(size_t)ks * NPATCH + gp0 + pt] = tacc;
}

// ---------------------------------------------------------------------------
// Finalize: wave per patch, lane = channel. Sum KS chunks (coalesced),
// bias+ReLU, dot wsum via shuffle; temp -> invT.
// ---------------------------------------------------------------------------
__global__ __launch_bounds__(256) void finalize_kernel(
    float* ws, const float* __restrict__ part, const float* __restrict__ tpart)
{
    int t    = threadIdx.x;
    int wv   = __builtin_amdgcn_readfirstlane(t >> 6);
    int lane = t & 63;
    int gp   = blockIdx.x * 4 + wv;   // 1024 blocks -> 4096 patches
    float v = 0.f;
    #pragma unroll
    for (int ks = 0; ks < KS; ++ks)
        v += part[((size_t)ks * NPATCH + gp) * 64 + lane];
    float h = fmaxf(v + ws[BIASP_OFF + lane], 0.f) * ws[WSUM_OFF + lane];
    #pragma unroll
    for (int off = 32; off; off >>= 1)
        h += __shfl_xor(h, off, 64);
    float ta = 0.f;
    #pragma unroll
    for (int ks = 0; ks < KS; ++ks)
        ta += tpart[(size_t)ks * NPATCH + gp];       // uniform -> s_load
    if (lane == 0) {
        float tval = fmaxf(ta + ws[MISC_OFF + 0], 0.f);
        ws[S_OFF + gp]    = h;
        ws[INVT_OFF + gp] = 1.0f / (0.025f + tval);
    }
}

// ---------------------------------------------------------------------------
// Fused 4-iteration softmax. One WAVE per query patch row; 1024 logits in
// 16 registers/lane; wave-shuffle reductions only.
// ---------------------------------------------------------------------------
__global__ __launch_bounds__(256) void softmax_kernel(
    const float* __restrict__ ws_ro, float* __restrict__ out)
{
    const float* sArr = ws_ro + S_OFF;
    const float* invT = ws_ro + INVT_OFF;
    int t    = threadIdx.x;
    int wv   = t >> 6;
    int lane = t & 63;
    int gp   = blockIdx.x * 4 + wv;   // 0..4095
    int b    = gp >> 10;
    int p    = gp & 1023;
    float sq = sArr[gp];
    float iT = invT[gp];
    const float4* srow = (const float4*)(sArr + (size_t)b * HWp);

    float L[16];
    #pragma unroll
    for (int c4 = 0; c4 < 4; ++c4) {
        float4 sv = srow[c4 * 64 + lane];
        int q0 = c4 * 256 + lane * 4;
        float d0 = sq - sv.x, d1 = sq - sv.y, d2 = sq - sv.z, d3 = sq - sv.w;
        L[c4*4+0] = -d0 * d0 * iT;
        L[c4*4+1] = -d1 * d1 * iT;
        L[c4*4+2] = -d2 * d2 * iT;
        L[c4*4+3] = -d3 * d3 * iT;
        if (q0 + 0 == p) L[c4*4+0] -= 1000.f * iT;
        if (q0 + 1 == p) L[c4*4+1] -= 1000.f * iT;
        if (q0 + 2 == p) L[c4*4+2] -= 1000.f * iT;
        if (q0 + 3 == p) L[c4*4+3] -= 1000.f * iT;
    }

    size_t rowOff = (size_t)gp * HWp;
    #pragma unroll 1
    for (int it = 0; it < 4; ++it) {
        float mx = L[0];
        #pragma unroll
        for (int j = 1; j < 16; ++j) mx = fmaxf(mx, L[j]);
        #pragma unroll
        for (int off = 32; off; off >>= 1)
            mx = fmaxf(mx, __shfl_xor(mx, off, 64));
        float e[16];
        float sum = 0.f;
        #pragma unroll
        for (int j = 0; j < 16; ++j) { e[j] = __expf(L[j] - mx); sum += e[j]; }
        #pragma unroll
        for (int off = 32; off; off >>= 1)
            sum += __shfl_xor(sum, off, 64);
        float r = 1.0f / sum;
        #pragma unroll
        for (int j = 0; j < 16; ++j) e[j] *= r;
        float4* orow = (float4*)(out + (size_t)it * NPATCH * HWp + rowOff);
        #pragma unroll
        for (int c4 = 0; c4 < 4; ++c4) {
            float4 o;
            o.x = e[c4*4+0]; o.y = e[c4*4+1]; o.z = e[c4*4+2]; o.w = e[c4*4+3];
            orow[c4 * 64 + lane] = o;
        }
        if (it < 3) {
            #pragma unroll
            for (int j = 0; j < 16; ++j)
                L[j] += iT * __logf(1.0f - e[j] + 1e-45f);
        }
    }
}

// ---------------------------------------------------------------------------
extern "C" void kernel_launch(void* const* d_in, const int* in_sizes, int n_in,
                              void* d_out, int out_size, void* d_ws, size_t ws_size,
                              hipStream_t stream)
{
    (void)in_sizes; (void)n_in; (void)out_size; (void)ws_size;
    const float* x       = (const float*)d_in[0];
    const float* conv1_w = (const float*)d_in[1];
    const float* conv1_b = (const float*)d_in[2];
    const float* bn1_g   = (const float*)d_in[3];
    const float* bn1_b   = (const float*)d_in[4];
    const float* bn1_m   = (const float*)d_in[5];
    const float* bn1_v   = (const float*)d_in[6];
    const float* conv2_w = (const float*)d_in[7];
    const float* conv2_b = (const float*)d_in[8];
    const float* tconv_w = (const float*)d_in[9];
    const float* tconv_b = (const float*)d_in[10];
    const float* bnt_g   = (const float*)d_in[11];
    const float* bnt_b   = (const float*)d_in[12];
    const float* bnt_m   = (const float*)d_in[13];
    const float* bnt_v   = (const float*)d_in[14];

    float* ws  = (float*)d_ws;
    float* out = (float*)d_out;

    prep_kernel<<<dim3(17), dim3(256), 0, stream>>>(
        conv1_w, conv1_b, bn1_g, bn1_b, bn1_m, bn1_v,
        conv2_w, conv2_b, tconv_w, tconv_b, bnt_g, bnt_b, bnt_m, bnt_v, ws);

    conv_kernel<<<dim3(128, KS), dim3(256), 0, stream>>>(
        x, ws, ws + PART_OFF, ws + TPART_OFF);

    finalize_kernel<<<dim3(1024), dim3(256), 0, stream>>>(
        ws, ws + PART_OFF, ws + TPART_OFF);

    softmax_kernel<<<dim3(1024), dim3(256), 0, stream>>>(ws, out);
}

// Round 7
// 61.542 us; speedup vs baseline: 1.7395x; 1.3913x over previous
//
#include <hip/hip_runtime.h>

// Problem constants
#define HWp    1024
#define NPATCH 4096
#define KS     8             // K-split chunks (8 ci each)

// ws layout. Bytes for the bf16 weight-fragment arrays:
#define WBH_B  0             // [128 ci2s][5 nt][64 lane][8 j] bf16 hi
#define WBL_B  655360        // same, lo
// Float offsets (floats region starts at byte 1310720 = float 327680):
#define BIASP_OFF 327680u    // [64] folded conv biases
#define WSUM_OFF  327744u    // [64] channel-sum of conv2_w
#define MISC_OFF  327808u    // [0]=bias_t
#define S_OFF     327824u    // [4096]
#define INVT_OFF  331920u    // [4096]
#define PART_OFF  336016u    // [KS][4096][64] fp32 conv partials
#define TPART_OFF 2433168u   // [KS][4096] temp partials

typedef short bf16x8 __attribute__((ext_vector_type(8)));
typedef float f32x4  __attribute__((ext_vector_type(4)));

// fp32 -> bf16 round-to-nearest-even, pure integer (no HIP bf16 types).
__device__ __forceinline__ unsigned f2bf(float f) {
    unsigned u = __float_as_uint(f);
    return (u + 0x7FFFu + ((u >> 16) & 1u)) >> 16;
}
__device__ __forceinline__ float bf2f(unsigned h) {
    return __uint_as_float(h << 16);
}

// Split 8 fp32 (two float4) into hi/lo bf16 fragments (8 bf16 = 16B each).
// hi = RNE(f); lo = RNE(f - float(hi)) with the residual basis exact, so
// A and B splits agree and pair packing is order-immune.
__device__ __forceinline__ void split_store(
    float4 qa, float4 qb, unsigned short* dh, unsigned short* dl)
{
    unsigned h0 = f2bf(qa.x), h1 = f2bf(qa.y), h2 = f2bf(qa.z), h3 = f2bf(qa.w);
    unsigned h4 = f2bf(qb.x), h5 = f2bf(qb.y), h6 = f2bf(qb.z), h7 = f2bf(qb.w);
    unsigned l0 = f2bf(qa.x - bf2f(h0)), l1 = f2bf(qa.y - bf2f(h1));
    unsigned l2 = f2bf(qa.z - bf2f(h2)), l3 = f2bf(qa.w - bf2f(h3));
    unsigned l4 = f2bf(qb.x - bf2f(h4)), l5 = f2bf(qb.y - bf2f(h5));
    unsigned l6 = f2bf(qb.z - bf2f(h6)), l7 = f2bf(qb.w - bf2f(h7));
    uint4 H, L;
    H.x = h0 | (h1 << 16); H.y = h2 | (h3 << 16);
    H.z = h4 | (h5 << 16); H.w = h6 | (h7 << 16);
    L.x = l0 | (l1 << 16); L.y = l2 | (l3 << 16);
    L.z = l4 | (l5 << 16); L.w = l6 | (l7 << 16);
    *(uint4*)dh = H;
    *(uint4*)dl = L;
}

// ---------------------------------------------------------------------------
// Prep. Blocks 0..159: build WBhi/WBlo in B-fragment order.
//   k = ci*64+ky*8+kx decomposed as (ci2s = k>>5, g = (k>>3)&3, j = k&7);
//   B-frag: lane = g*16 + (ch&15), nt = ch>>4 (nt==4: col0 = temp weights,
//   cols 1..15 zero). Thread = (kq = k>>3, cx 0..79).
// Block 160: scalar folds (bias, wsum, bias_t).
// ---------------------------------------------------------------------------
__global__ void prep_kernel(
    const float* __restrict__ conv1_w, const float* __restrict__ conv1_b,
    const float* __restrict__ g,  const float* __restrict__ bb,
    const float* __restrict__ m,  const float* __restrict__ v,
    const float* __restrict__ conv2_w, const float* __restrict__ conv2_b,
    const float* __restrict__ tconv_w, const float* __restrict__ tconv_b,
    const float* __restrict__ tg, const float* __restrict__ tb,
    const float* __restrict__ tm, const float* __restrict__ tv,
    float* __restrict__ ws)
{
    unsigned short* WBH = (unsigned short*)((char*)ws + WBH_B);
    unsigned short* WBL = (unsigned short*)((char*)ws + WBL_B);
    if (blockIdx.x < 160) {
        int idx = blockIdx.x * 256 + threadIdx.x;
        if (idx >= 40960) return;
        int kq = idx / 80, cx = idx % 80;
        int k0 = kq * 8;
        float f0,f1,f2,f3,f4,f5,f6,f7;
        if (cx < 64) {
            float A = g[cx] / sqrtf(v[cx] + 1e-5f);
            const float* w = conv1_w + (size_t)cx * 4096 + k0;
            f0=A*w[0]; f1=A*w[1]; f2=A*w[2]; f3=A*w[3];
            f4=A*w[4]; f5=A*w[5]; f6=A*w[6]; f7=A*w[7];
        } else if (cx == 64) {
            float At = tg[0] / sqrtf(tv[0] + 1e-5f);
            const float* w = tconv_w + k0;
            f0=At*w[0]; f1=At*w[1]; f2=At*w[2]; f3=At*w[3];
            f4=At*w[4]; f5=At*w[5]; f6=At*w[6]; f7=At*w[7];
        } else {
            f0=f1=f2=f3=f4=f5=f6=f7=0.f;
        }
        int dst = (((kq >> 2) * 5 + (cx >> 4)) * 512
                   + ((kq & 3) * 16 + (cx & 15)) * 8);
        split_store(make_float4(f0,f1,f2,f3), make_float4(f4,f5,f6,f7),
                    WBH + dst, WBL + dst);
    } else {
        int t = threadIdx.x;
        if (t < 64) {
            float A = g[t] / sqrtf(v[t] + 1e-5f);
            ws[BIASP_OFF + t] = A * (conv1_b[t] - m[t]) + bb[t];
            float s = 0.f;
            for (int co = 0; co < 64; ++co) s += conv2_w[co * 64 + t];
            ws[WSUM_OFF + t] = s;
        } else if (t == 64) {
            float At = tg[0] / sqrtf(tv[0] + 1e-5f);
            ws[MISC_OFF + 0] = At * (tconv_b[0] - tm[0]) + tb[0];
        }
    }
}

// ---------------------------------------------------------------------------
// MFMA conv. Block = 256 thr = 4 waves, 64 patches (wave wv: 16), K-chunk =
// 8 ci (blockIdx.y). Per ci: stage x tile fp32 -> hi/lo bf16 into LDS in
// A-fragment order (double-buffered, one barrier/ci); MFMA 16x16x32_bf16,
// 5 N-tiles (64 ch + temp), 3 mfma per tile (hh, hl, lh split).
// A-frag: lane l holds row=l&15, k=(l>>4)*8+j.  D: col=l&15, row=(l>>4)*4+r.
// ---------------------------------------------------------------------------
__global__ __launch_bounds__(256, 2) void conv_kernel(
    const float* __restrict__ x, const void* __restrict__ wsv,
    float* __restrict__ part, float* __restrict__ tpart)
{
    // [hl 2][buf 2][wd 4][s 2][lane 64][j 8] bf16 = 32 KB
    __shared__ __align__(16) unsigned short ldsA[16384];
    const unsigned short* WBH = (const unsigned short*)((const char*)wsv + WBH_B);
    const unsigned short* WBL = (const unsigned short*)((const char*)wsv + WBL_B);
    int t  = threadIdx.x;
    int wv = t >> 6, l = t & 63;
    int mb = blockIdx.x;          // 64 M-blocks (b*16 + pyq)
    int kb = blockIdx.y;          // 8 K-chunks
    int b  = mb >> 4, pyq = mb & 15;

    // staging coords: thread t -> (row rr 0..15, seg 0..15)
    int rr  = t >> 4, seg = t & 15;
    int rowg = (pyq * 2 + (rr >> 3)) * 8 + (rr & 7);
    int sS = (rr >> 2) & 1;
    int gS = rr & 3;
    int pl0 = (rr >> 3) * 32 + seg * 2;
    int wd0 = pl0 >> 4, ld0 = (gS << 4) | (pl0 & 15);
    int pl1 = pl0 + 1;
    int wd1 = pl1 >> 4, ld1 = (gS << 4) | (pl1 & 15);
    const float* xbase = x + ((size_t)(b * 64 + kb * 8) << 16) + rowg * 256 + seg * 16;

    f32x4 acc0 = {0.f,0.f,0.f,0.f}, acc1 = acc0, acc2 = acc0, acc3 = acc0, acc4 = acc0;

    float4 q0, q1, q2, q3;
    { const float4* p = (const float4*)xbase; q0 = p[0]; q1 = p[1]; q2 = p[2]; q3 = p[3]; }
    {
        int base0 = wd0 * 1024 + sS * 512 + ld0 * 8;
        int base1 = wd1 * 1024 + sS * 512 + ld1 * 8;
        split_store(q0, q1, &ldsA[base0], &ldsA[8192 + base0]);
        split_store(q2, q3, &ldsA[base1], &ldsA[8192 + base1]);
    }
    __syncthreads();

    for (int ci = 0; ci < 8; ++ci) {
        int buf = ci & 1;
        if (ci < 7) {
            const float4* p = (const float4*)(xbase + ((size_t)(ci + 1) << 16));
            q0 = p[0]; q1 = p[1]; q2 = p[2]; q3 = p[3];
        }
        #pragma unroll
        for (int s = 0; s < 2; ++s) {
            const unsigned short* ap = &ldsA[(buf * 8 + wv * 2 + s) * 512 + l * 8];
            bf16x8 ah = *(const bf16x8*)ap;
            bf16x8 al = *(const bf16x8*)(ap + 8192);
            int cb = ((kb * 8 + ci) * 2 + s) * 5;
            const unsigned short* wbH = WBH + cb * 512 + l * 8;
            const unsigned short* wbL = WBL + cb * 512 + l * 8;
            #define MTILE(NT, ACC) do {                                        \
                bf16x8 bh = *(const bf16x8*)(wbH + (NT) * 512);                \
                bf16x8 bl = *(const bf16x8*)(wbL + (NT) * 512);                \
                ACC = __builtin_amdgcn_mfma_f32_16x16x32_bf16(ah, bh, ACC, 0, 0, 0); \
                ACC = __builtin_amdgcn_mfma_f32_16x16x32_bf16(ah, bl, ACC, 0, 0, 0); \
                ACC = __builtin_amdgcn_mfma_f32_16x16x32_bf16(al, bh, ACC, 0, 0, 0); \
            } while (0)
            MTILE(0, acc0); MTILE(1, acc1); MTILE(2, acc2);
            MTILE(3, acc3); MTILE(4, acc4);
            #undef MTILE
        }
        if (ci < 7) {
            int wb = (buf ^ 1) * 4096;
            int base0 = wb + wd0 * 1024 + sS * 512 + ld0 * 8;
            int base1 = wb + wd1 * 1024 + sS * 512 + ld1 * 8;
            split_store(q0, q1, &ldsA[base0], &ldsA[8192 + base0]);
            split_store(q2, q3, &ldsA[base1], &ldsA[8192 + base1]);
        }
        __syncthreads();
    }

    // epilogue: D col=l&15 (ch), row=(l>>4)*4+r (patch)
    int pr = (l >> 4) * 4;
    int ch = l & 15;
    size_t pb = ((size_t)kb * NPATCH + mb * 64 + wv * 16 + pr) * 64 + ch;
    #pragma unroll
    for (int r2 = 0; r2 < 4; ++r2) {
        part[pb + r2 * 64     ] = acc0[r2];
        part[pb + r2 * 64 + 16] = acc1[r2];
        part[pb + r2 * 64 + 32] = acc2[r2];
        part[pb + r2 * 64 + 48] = acc3[r2];
    }
    if (ch == 0) {
        int tbase = kb * NPATCH + mb * 64 + wv * 16 + pr;
        #pragma unroll
        for (int r2 = 0; r2 < 4; ++r2) tpart[tbase + r2] = acc4[r2];
    }
}

// ---------------------------------------------------------------------------
// Finalize: wave per patch, lane = channel. Sum KS chunks, bias+ReLU,
// dot wsum via shuffle; temp -> invT.
// ---------------------------------------------------------------------------
__global__ __launch_bounds__(256) void finalize_kernel(
    float* ws, const float* __restrict__ part, const float* __restrict__ tpart)
{
    int t    = threadIdx.x;
    int wv   = __builtin_amdgcn_readfirstlane(t >> 6);
    int lane = t & 63;
    int gp   = blockIdx.x * 4 + wv;
    float v = 0.f;
    #pragma unroll
    for (int ks = 0; ks < KS; ++ks)
        v += part[((size_t)ks * NPATCH + gp) * 64 + lane];
    float h = fmaxf(v + ws[BIASP_OFF + lane], 0.f) * ws[WSUM_OFF + lane];
    #pragma unroll
    for (int off = 32; off; off >>= 1)
        h += __shfl_xor(h, off, 64);
    float ta = 0.f;
    #pragma unroll
    for (int ks = 0; ks < KS; ++ks)
        ta += tpart[(size_t)ks * NPATCH + gp];
    if (lane == 0) {
        float tval = fmaxf(ta + ws[MISC_OFF + 0], 0.f);
        ws[S_OFF + gp]    = h;
        ws[INVT_OFF + gp] = 1.0f / (0.025f + tval);
    }
}

// ---------------------------------------------------------------------------
// Fused 4-iteration softmax (unchanged structure).
// ---------------------------------------------------------------------------
__global__ __launch_bounds__(256) void softmax_kernel(
    const float* __restrict__ ws_ro, float* __restrict__ out)
{
    const float* sArr = ws_ro + S_OFF;
    const float* invT = ws_ro + INVT_OFF;
    int t    = threadIdx.x;
    int wv   = t >> 6;
    int lane = t & 63;
    int gp   = blockIdx.x * 4 + wv;
    int b    = gp >> 10;
    int p    = gp & 1023;
    float sq = sArr[gp];
    float iT = invT[gp];
    const float4* srow = (const float4*)(sArr + (size_t)b * HWp);

    float L[16];
    #pragma unroll
    for (int c4 = 0; c4 < 4; ++c4) {
        float4 sv = srow[c4 * 64 + lane];
        int q0 = c4 * 256 + lane * 4;
        float d0 = sq - sv.x, d1 = sq - sv.y, d2 = sq - sv.z, d3 = sq - sv.w;
        L[c4*4+0] = -d0 * d0 * iT;
        L[c4*4+1] = -d1 * d1 * iT;
        L[c4*4+2] = -d2 * d2 * iT;
        L[c4*4+3] = -d3 * d3 * iT;
        if (q0 + 0 == p) L[c4*4+0] -= 1000.f * iT;
        if (q0 + 1 == p) L[c4*4+1] -= 1000.f * iT;
        if (q0 + 2 == p) L[c4*4+2] -= 1000.f * iT;
        if (q0 + 3 == p) L[c4*4+3] -= 1000.f * iT;
    }

    size_t rowOff = (size_t)gp * HWp;
    #pragma unroll 1
    for (int it = 0; it < 4; ++it) {
        float mx = L[0];
        #pragma unroll
        for (int j = 1; j < 16; ++j) mx = fmaxf(mx, L[j]);
        #pragma unroll
        for (int off = 32; off; off >>= 1)
            mx = fmaxf(mx, __shfl_xor(mx, off, 64));
        float e[16];
        float sum = 0.f;
        #pragma unroll
        for (int j = 0; j < 16; ++j) { e[j] = __expf(L[j] - mx); sum += e[j]; }
        #pragma unroll
        for (int off = 32; off; off >>= 1)
            sum += __shfl_xor(sum, off, 64);
        float r = 1.0f / sum;
        #pragma unroll
        for (int j = 0; j < 16; ++j) e[j] *= r;
        float4* orow = (float4*)(out + (size_t)it * NPATCH * HWp + rowOff);
        #pragma unroll
        for (int c4 = 0; c4 < 4; ++c4) {
            float4 o;
            o.x = e[c4*4+0]; o.y = e[c4*4+1]; o.z = e[c4*4+2]; o.w = e[c4*4+3];
            orow[c4 * 64 + lane] = o;
        }
        if (it < 3) {
            #pragma unroll
            for (int j = 0; j < 16; ++j)
                L[j] += iT * __logf(1.0f - e[j] + 1e-45f);
        }
    }
}

// ---------------------------------------------------------------------------
extern "C" void kernel_launch(void* const* d_in, const int* in_sizes, int n_in,
                              void* d_out, int out_size, void* d_ws, size_t ws_size,
                              hipStream_t stream)
{
    (void)in_sizes; (void)n_in; (void)out_size; (void)ws_size;
    const float* x       = (const float*)d_in[0];
    const float* conv1_w = (const float*)d_in[1];
    const float* conv1_b = (const float*)d_in[2];
    const float* bn1_g   = (const float*)d_in[3];
    const float* bn1_b   = (const float*)d_in[4];
    const float* bn1_m   = (const float*)d_in[5];
    const float* bn1_v   = (const float*)d_in[6];
    const float* conv2_w = (const float*)d_in[7];
    const float* conv2_b = (const float*)d_in[8];
    const float* tconv_w = (const float*)d_in[9];
    const float* tconv_b = (const float*)d_in[10];
    const float* bnt_g   = (const float*)d_in[11];
    const float* bnt_b   = (const float*)d_in[12];
    const float* bnt_m   = (const float*)d_in[13];
    const float* bnt_v   = (const float*)d_in[14];

    float* ws  = (float*)d_ws;
    float* out = (float*)d_out;

    prep_kernel<<<dim3(161), dim3(256), 0, stream>>>(
        conv1_w, conv1_b, bn1_g, bn1_b, bn1_m, bn1_v,
        conv2_w, conv2_b, tconv_w, tconv_b, bnt_g, bnt_b, bnt_m, bnt_v, ws);

    conv_kernel<<<dim3(64, KS), dim3(256), 0, stream>>>(
        x, ws, ws + PART_OFF, ws + TPART_OFF);

    finalize_kernel<<<dim3(1024), dim3(256), 0, stream>>>(
        ws, ws + PART_OFF, ws + TPART_OFF);

    softmax_kernel<<<dim3(1024), dim3(256), 0, stream>>>(ws, out);
}

// Round 9
// 48.412 us; speedup vs baseline: 2.2113x; 1.2712x over previous
//
#include <hip/hip_runtime.h>

// Problem constants
#define HWp    1024
#define NPATCH 4096
#define KS     16            // K-split chunks (4 ci each)

// ws layout. Bytes for the bf16 weight-fragment arrays:
#define WBH_B  0             // [128 ci2s][5 nt][64 lane][8 j] bf16 hi
#define WBL_B  655360        // same, lo
// Float offsets (floats region starts at byte 1310720 = float 327680):
#define BIASP_OFF 327680u    // [64] folded conv biases
#define WSUM_OFF  327744u    // [64] channel-sum of conv2_w
#define MISC_OFF  327808u    // [0]=bias_t
#define S_OFF     327824u    // [4096]
#define INVT_OFF  331920u    // [4096]
#define PART_OFF  336016u    // [KS][4096][64] fp32 conv partials
#define TPART_OFF 4530320u   // [KS][4096] temp partials

typedef short bf16x8 __attribute__((ext_vector_type(8)));
typedef float f32x4  __attribute__((ext_vector_type(4)));

// fp32 -> bf16 round-to-nearest-even, pure integer (no HIP bf16 types).
__device__ __forceinline__ unsigned f2bf(float f) {
    unsigned u = __float_as_uint(f);
    return (u + 0x7FFFu + ((u >> 16) & 1u)) >> 16;
}
__device__ __forceinline__ float bf2f(unsigned h) {
    return __uint_as_float(h << 16);
}

// Split 8 fp32 (two float4) into hi/lo bf16 fragments (8 bf16 = 16B each).
// hi = RNE(f); lo = RNE(f - float(hi)); residual basis exact, so A and B
// splits agree and pair packing is order-immune.
__device__ __forceinline__ void split_store(
    float4 qa, float4 qb, unsigned short* dh, unsigned short* dl)
{
    unsigned h0 = f2bf(qa.x), h1 = f2bf(qa.y), h2 = f2bf(qa.z), h3 = f2bf(qa.w);
    unsigned h4 = f2bf(qb.x), h5 = f2bf(qb.y), h6 = f2bf(qb.z), h7 = f2bf(qb.w);
    unsigned l0 = f2bf(qa.x - bf2f(h0)), l1 = f2bf(qa.y - bf2f(h1));
    unsigned l2 = f2bf(qa.z - bf2f(h2)), l3 = f2bf(qa.w - bf2f(h3));
    unsigned l4 = f2bf(qb.x - bf2f(h4)), l5 = f2bf(qb.y - bf2f(h5));
    unsigned l6 = f2bf(qb.z - bf2f(h6)), l7 = f2bf(qb.w - bf2f(h7));
    uint4 H, L;
    H.x = h0 | (h1 << 16); H.y = h2 | (h3 << 16);
    H.z = h4 | (h5 << 16); H.w = h6 | (h7 << 16);
    L.x = l0 | (l1 << 16); L.y = l2 | (l3 << 16);
    L.z = l4 | (l5 << 16); L.w = l6 | (l7 << 16);
    *(uint4*)dh = H;
    *(uint4*)dl = L;
}

// ---------------------------------------------------------------------------
// Prep. Blocks 0..159: build WBhi/WBlo in B-fragment order.
//   k = ci*64+ky*8+kx -> (ci2s = k>>5, g = (k>>3)&3, j = k&7);
//   B-frag: lane = g*16 + (ch&15), nt = ch>>4 (nt==4: col0 = temp weights,
//   cols 1..15 zero). Thread = (kq = k>>3, cx 0..79).
// Block 160: scalar folds (bias, wsum, bias_t).
// ---------------------------------------------------------------------------
__global__ void prep_kernel(
    const float* __restrict__ conv1_w, const float* __restrict__ conv1_b,
    const float* __restrict__ g,  const float* __restrict__ bb,
    const float* __restrict__ m,  const float* __restrict__ v,
    const float* __restrict__ conv2_w, const float* __restrict__ conv2_b,
    const float* __restrict__ tconv_w, const float* __restrict__ tconv_b,
    const float* __restrict__ tg, const float* __restrict__ tb,
    const float* __restrict__ tm, const float* __restrict__ tv,
    float* __restrict__ ws)
{
    unsigned short* WBH = (unsigned short*)((char*)ws + WBH_B);
    unsigned short* WBL = (unsigned short*)((char*)ws + WBL_B);
    if (blockIdx.x < 160) {
        int idx = blockIdx.x * 256 + threadIdx.x;
        if (idx >= 40960) return;
        int kq = idx / 80, cx = idx % 80;
        int k0 = kq * 8;
        float f0,f1,f2,f3,f4,f5,f6,f7;
        if (cx < 64) {
            float A = g[cx] / sqrtf(v[cx] + 1e-5f);
            const float* w = conv1_w + (size_t)cx * 4096 + k0;
            f0=A*w[0]; f1=A*w[1]; f2=A*w[2]; f3=A*w[3];
            f4=A*w[4]; f5=A*w[5]; f6=A*w[6]; f7=A*w[7];
        } else if (cx == 64) {
            float At = tg[0] / sqrtf(tv[0] + 1e-5f);
            const float* w = tconv_w + k0;
            f0=At*w[0]; f1=At*w[1]; f2=At*w[2]; f3=At*w[3];
            f4=At*w[4]; f5=At*w[5]; f6=At*w[6]; f7=At*w[7];
        } else {
            f0=f1=f2=f3=f4=f5=f6=f7=0.f;
        }
        int dst = (((kq >> 2) * 5 + (cx >> 4)) * 512
                   + ((kq & 3) * 16 + (cx & 15)) * 8);
        split_store(make_float4(f0,f1,f2,f3), make_float4(f4,f5,f6,f7),
                    WBH + dst, WBL + dst);
    } else {
        int t = threadIdx.x;
        if (t < 64) {
            float A = g[t] / sqrtf(v[t] + 1e-5f);
            ws[BIASP_OFF + t] = A * (conv1_b[t] - m[t]) + bb[t];
            float s = 0.f;
            for (int co = 0; co < 64; ++co) s += conv2_w[co * 64 + t];
            ws[WSUM_OFF + t] = s;
        } else if (t == 64) {
            float At = tg[0] / sqrtf(tv[0] + 1e-5f);
            ws[MISC_OFF + 0] = At * (tconv_b[0] - tm[0]) + tb[0];
        }
    }
}

// ---------------------------------------------------------------------------
// MFMA conv. Block = 256 thr = 4 waves, 64 patches (wave wv: 16), K-chunk =
// 4 ci (blockIdx.y, 16 chunks). Staging map == fragment map: thread t
// stages fragment (wd = t>>6, lane = t&63) for s in {0,1} -> each thread
// loads 8 contiguous floats and writes lane-consecutive 16B chunks
// (conflict-free LDS, coalesced global). Double-buffered, 1 barrier/ci.
// MFMA 16x16x32_bf16, 5 N-tiles (64 ch + temp), 3 mfma per tile (hi/lo split).
// A-frag: lane l holds row=l&15, k=(l>>4)*8+j.  D: col=l&15, row=(l>>4)*4+r.
// ---------------------------------------------------------------------------
__global__ __launch_bounds__(256, 5) void conv_kernel(
    const float* __restrict__ x, const void* __restrict__ wsv,
    float* __restrict__ part, float* __restrict__ tpart)
{
    // [hl 2][buf 2][wd 4][s 2][lane 64][j 8] bf16 = 32 KB
    __shared__ __align__(16) unsigned short ldsA[16384];
    const unsigned short* WBH = (const unsigned short*)((const char*)wsv + WBH_B);
    const unsigned short* WBL = (const unsigned short*)((const char*)wsv + WBL_B);
    int t  = threadIdx.x;
    int wv = t >> 6, l = t & 63;
    int mb = blockIdx.x;          // 64 M-blocks (b*16 + pyq)
    int kb = blockIdx.y;          // 16 K-chunks
    int b  = mb >> 4, pyq = mb & 15;
    int ci0 = kb * 4;

    // staging coords (thread t stages fragment wd=wv, lane=l, s=0/1)
    int sp   = wv * 16 + (l & 15);            // patch 0..63
    int srow = (pyq * 2 + (sp >> 5)) * 8 + (l >> 4);   // + s*4
    int spx  = sp & 31;
    const float* xs = x + ((size_t)(b * 64 + ci0) << 16) + srow * 256 + spx * 8;
    int dfr = wv * 1024 + l * 8;              // (wv*2+0)*512 + l*8; s=1: +512

    f32x4 acc0 = {0.f,0.f,0.f,0.f}, acc1 = acc0, acc2 = acc0, acc3 = acc0, acc4 = acc0;

    float4 q0, q1, q2, q3;
    #define LOADX(CI) do {                                                    \
        const float* _x0 = xs + ((size_t)(CI) << 16);                         \
        q0 = ((const float4*)_x0)[0]; q1 = ((const float4*)_x0)[1];           \
        q2 = ((const float4*)(_x0 + 1024))[0];                                \
        q3 = ((const float4*)(_x0 + 1024))[1];                                \
    } while (0)
    #define STOREX(BUF) do {                                                  \
        int _d = (BUF) * 4096 + dfr;                                          \
        split_store(q0, q1, &ldsA[_d],       &ldsA[8192 + _d]);               \
        split_store(q2, q3, &ldsA[_d + 512], &ldsA[8192 + _d + 512]);         \
    } while (0)

    LOADX(0);
    STOREX(0);
    __syncthreads();

    for (int ci = 0; ci < 4; ++ci) {
        int buf = ci & 1;
        if (ci < 3) LOADX(ci + 1);
        #pragma unroll
        for (int s = 0; s < 2; ++s) {
            const unsigned short* ap = &ldsA[buf * 4096 + (wv * 2 + s) * 512 + l * 8];
            bf16x8 ah = *(const bf16x8*)ap;
            bf16x8 al = *(const bf16x8*)(ap + 8192);
            int cb = ((ci0 + ci) * 2 + s) * 5;
            const unsigned short* wbH = WBH + cb * 512 + l * 8;
            const unsigned short* wbL = WBL + cb * 512 + l * 8;
            #define MTILE(NT, ACC) do {                                        \
                bf16x8 bh = *(const bf16x8*)(wbH + (NT) * 512);                \
                bf16x8 bl = *(const bf16x8*)(wbL + (NT) * 512);                \
                ACC = __builtin_amdgcn_mfma_f32_16x16x32_bf16(ah, bh, ACC, 0, 0, 0); \
                ACC = __builtin_amdgcn_mfma_f32_16x16x32_bf16(ah, bl, ACC, 0, 0, 0); \
                ACC = __builtin_amdgcn_mfma_f32_16x16x32_bf16(al, bh, ACC, 0, 0, 0); \
            } while (0)
            MTILE(0, acc0); MTILE(1, acc1); MTILE(2, acc2);
            MTILE(3, acc3); MTILE(4, acc4);
            #undef MTILE
        }
        if (ci < 3) STOREX(buf ^ 1);
        __syncthreads();
    }
    #undef LOADX
    #undef STOREX

    // epilogue: D col=l&15 (ch), row=(l>>4)*4+r (patch)
    int pr = (l >> 4) * 4;
    int ch = l & 15;
    size_t pb = ((size_t)kb * NPATCH + mb * 64 + wv * 16 + pr) * 64 + ch;
    #pragma unroll
    for (int r2 = 0; r2 < 4; ++r2) {
        part[pb + r2 * 64     ] = acc0[r2];
        part[pb + r2 * 64 + 16] = acc1[r2];
        part[pb + r2 * 64 + 32] = acc2[r2];
        part[pb + r2 * 64 + 48] = acc3[r2];
    }
    if (ch == 0) {
        int tbase = kb * NPATCH + mb * 64 + wv * 16 + pr;
        #pragma unroll
        for (int r2 = 0; r2 < 4; ++r2) tpart[tbase + r2] = acc4[r2];
    }
}

// ---------------------------------------------------------------------------
// Finalize: wave per patch, lane = channel. Sum KS chunks, bias+ReLU,
// dot wsum via shuffle; temp -> invT.
// ---------------------------------------------------------------------------
__global__ __launch_bounds__(256) void finalize_kernel(
    float* ws, const float* __restrict__ part, const float* __restrict__ tpart)
{
    int t    = threadIdx.x;
    int wv   = __builtin_amdgcn_readfirstlane(t >> 6);
    int lane = t & 63;
    int gp   = blockIdx.x * 4 + wv;
    float v = 0.f;
    #pragma unroll
    for (int ks = 0; ks < KS; ++ks)
        v += part[((size_t)ks * NPATCH + gp) * 64 + lane];
    float h = fmaxf(v + ws[BIASP_OFF + lane], 0.f) * ws[WSUM_OFF + lane];
    #pragma unroll
    for (int off = 32; off; off >>= 1)
        h += __shfl_xor(h, off, 64);
    float ta = 0.f;
    #pragma unroll
    for (int ks = 0; ks < KS; ++ks)
        ta += tpart[(size_t)ks * NPATCH + gp];
    if (lane == 0) {
        float tval = fmaxf(ta + ws[MISC_OFF + 0], 0.f);
        ws[S_OFF + gp]    = h;
        ws[INVT_OFF + gp] = 1.0f / (0.025f + tval);
    }
}

// ---------------------------------------------------------------------------
// Fused 4-iteration softmax. One WAVE per query patch row; 1024 logits in
// 16 registers/lane; wave-shuffle reductions only. Nontemporal output
// stores (268 MB pure stream, keep it out of L2).
// ---------------------------------------------------------------------------
__global__ __launch_bounds__(256) void softmax_kernel(
    const float* __restrict__ ws_ro, float* __restrict__ out)
{
    const float* sArr = ws_ro + S_OFF;
    const float* invT = ws_ro + INVT_OFF;
    int t    = threadIdx.x;
    int wv   = t >> 6;
    int lane = t & 63;
    int gp   = blockIdx.x * 4 + wv;
    int b    = gp >> 10;
    int p    = gp & 1023;
    float sq = sArr[gp];
    float iT = invT[gp];
    const float4* srow = (const float4*)(sArr + (size_t)b * HWp);

    float L[16];
    #pragma unroll
    for (int c4 = 0; c4 < 4; ++c4) {
        float4 sv = srow[c4 * 64 + lane];
        int q0 = c4 * 256 + lane * 4;
        float d0 = sq - sv.x, d1 = sq - sv.y, d2 = sq - sv.z, d3 = sq - sv.w;
        L[c4*4+0] = -d0 * d0 * iT;
        L[c4*4+1] = -d1 * d1 * iT;
        L[c4*4+2] = -d2 * d2 * iT;
        L[c4*4+3] = -d3 * d3 * iT;
        if (q0 + 0 == p) L[c4*4+0] -= 1000.f * iT;
        if (q0 + 1 == p) L[c4*4+1] -= 1000.f * iT;
        if (q0 + 2 == p) L[c4*4+2] -= 1000.f * iT;
        if (q0 + 3 == p) L[c4*4+3] -= 1000.f * iT;
    }

    size_t rowOff = (size_t)gp * HWp;
    #pragma unroll 1
    for (int it = 0; it < 4; ++it) {
        float mx = L[0];
        #pragma unroll
        for (int j = 1; j < 16; ++j) mx = fmaxf(mx, L[j]);
        #pragma unroll
        for (int off = 32; off; off >>= 1)
            mx = fmaxf(mx, __shfl_xor(mx, off, 64));
        float e[16];
        float sum = 0.f;
        #pragma unroll
        for (int j = 0; j < 16; ++j) { e[j] = __expf(L[j] - mx); sum += e[j]; }
        #pragma unroll
        for (int off = 32; off; off >>= 1)
            sum += __shfl_xor(sum, off, 64);
        float r = 1.0f / sum;
        #pragma unroll
        for (int j = 0; j < 16; ++j) e[j] *= r;
        f32x4* orow = (f32x4*)(out + (size_t)it * NPATCH * HWp + rowOff);
        #pragma unroll
        for (int c4 = 0; c4 < 4; ++c4) {
            f32x4 o = { e[c4*4+0], e[c4*4+1], e[c4*4+2], e[c4*4+3] };
            __builtin_nontemporal_store(o, &orow[c4 * 64 + lane]);
        }
        if (it < 3) {
            #pragma unroll
            for (int j = 0; j < 16; ++j)
                L[j] += iT * __logf(1.0f - e[j] + 1e-45f);
        }
    }
}

// ---------------------------------------------------------------------------
extern "C" void kernel_launch(void* const* d_in, const int* in_sizes, int n_in,
                              void* d_out, int out_size, void* d_ws, size_t ws_size,
                              hipStream_t stream)
{
    (void)in_sizes; (void)n_in; (void)out_size; (void)ws_size;
    const float* x       = (const float*)d_in[0];
    const float* conv1_w = (const float*)d_in[1];
    const float* conv1_b = (const float*)d_in[2];
    const float* bn1_g   = (const float*)d_in[3];
    const float* bn1_b   = (const float*)d_in[4];
    const float* bn1_m   = (const float*)d_in[5];
    const float* bn1_v   = (const float*)d_in[6];
    const float* conv2_w = (const float*)d_in[7];
    const float* conv2_b = (const float*)d_in[8];
    const float* tconv_w = (const float*)d_in[9];
    const float* tconv_b = (const float*)d_in[10];
    const float* bnt_g   = (const float*)d_in[11];
    const float* bnt_b   = (const float*)d_in[12];
    const float* bnt_m   = (const float*)d_in[13];
    const float* bnt_v   = (const float*)d_in[14];

    float* ws  = (float*)d_ws;
    float* out = (float*)d_out;

    prep_kernel<<<dim3(161), dim3(256), 0, stream>>>(
        conv1_w, conv1_b, bn1_g, bn1_b, bn1_m, bn1_v,
        conv2_w, conv2_b, tconv_w, tconv_b, bnt_g, bnt_b, bnt_m, bnt_v, ws);

    conv_kernel<<<dim3(64, KS), dim3(256), 0, stream>>>(
        x, ws, ws + PART_OFF, ws + TPART_OFF);

    finalize_kernel<<<dim3(1024), dim3(256), 0, stream>>>(
        ws, ws + PART_OFF, ws + TPART_OFF);

    softmax_kernel<<<dim3(1024), dim3(256), 0, stream>>>(ws, out);
}